// Round 6
// baseline (272.041 us; speedup 1.0000x reference)
//
#include <hip/hip_runtime.h>
#include <hip/hip_bf16.h>
#include <math.h>

constexpr int NSEQ = 192;
constexpr int DIM  = 128;
constexpr int NH   = 4;
constexpr int DHEAD = 32;
constexpr int MROWS = NSEQ * NSEQ; // 36864

typedef __hip_bfloat16 bf16;
typedef __attribute__((ext_vector_type(8))) short bf16x8;
typedef __attribute__((ext_vector_type(4))) float f32x4;
typedef unsigned int u32;

__device__ __forceinline__ void gload16(const void* g, void* l) {
    __builtin_amdgcn_global_load_lds(
        (const __attribute__((address_space(1))) u32*)g,
        (__attribute__((address_space(3))) u32*)l, 16, 0, 0);
}

__device__ __forceinline__ short f2bs(float f) {
    __hip_bfloat16 h = __float2bfloat16(f);
    return *(short*)&h;
}

// ---------------- prep: weight convert (blocks 0..1411) + LN1+biasproj (rest) ----------
__global__ __launch_bounds__(256)
void prep_kernel(const float* __restrict__ wq_o, const float* __restrict__ wkv_o,
                 const float* __restrict__ wg_o,
                 const float* __restrict__ wq_i, const float* __restrict__ wkv_i,
                 const float* __restrict__ wg_i,
                 const float* __restrict__ wo_o, const float* __restrict__ wo_i,
                 const float* __restrict__ w1, const float* __restrict__ b1,
                 const float* __restrict__ w2,
                 bf16* __restrict__ WQKVG_O, bf16* __restrict__ WQKVG_I,
                 bf16* __restrict__ WOT_O, bf16* __restrict__ WOT_I,
                 bf16* __restrict__ W1PT, bf16* __restrict__ W2T,
                 float* __restrict__ B1P,
                 const float* __restrict__ x, const float* __restrict__ lng,
                 const float* __restrict__ lnb, const float* __restrict__ wb,
                 bf16* __restrict__ xa, float* __restrict__ bias)
{
    if (blockIdx.x < 1412) {
        int idx = blockIdx.x * 256 + threadIdx.x;
        const float scale = 0.17677669529663689f; // 32^-0.5 folded into wq
        if (idx < 131072) {                       // WQKVG_{o,i}: [512][128], rows q|k|v|g
            int s = idx >> 16, i = idx & 65535;
            int r = i >> 7, d = i & 127;
            const float* wq  = s ? wq_i  : wq_o;
            const float* wkv = s ? wkv_i : wkv_o;
            const float* wg  = s ? wg_i  : wg_o;
            float v;
            if (r < 128)      v = wq[d * 128 + r] * scale;
            else if (r < 384) v = wkv[d * 256 + (r - 128)];
            else              v = wg[d * 128 + (r - 384)];
            (s ? WQKVG_I : WQKVG_O)[i] = __float2bfloat16(v);
        } else if (idx < 163840) {                // WOT_{o,i}: [128][128] = wo^T
            int i = idx - 131072; int s = i >> 14; i &= 16383;
            int r = i >> 7, d = i & 127;
            (s ? WOT_I : WOT_O)[i] = __float2bfloat16((s ? wo_i : wo_o)[d * 128 + r]);
        } else if (idx < 294912) {                // W1PT: [1024][128], rows 2j=a_j, 2j+1=g_j
            int i = idx - 163840;
            int r = i >> 7, d = i & 127;
            int col = (r & 1) ? 512 + (r >> 1) : (r >> 1);
            W1PT[i] = __float2bfloat16(w1[d * 1024 + col]);
        } else if (idx < 360448) {                // W2T: [128][512] = w2^T
            int i = idx - 294912;
            int n = i >> 9, k = i & 511;
            W2T[i] = __float2bfloat16(w2[k * 128 + n]);
        } else if (idx < 361472) {                // B1P: paired bias
            int r = idx - 360448;
            B1P[r] = b1[(r & 1) ? 512 + (r >> 1) : (r >> 1)];
        }
        return;
    }
    // ---- LN1 + bias projection, vectorized (lane owns elems 2l, 2l+1) ----
    int wid  = threadIdx.x >> 6;
    int lane = threadIdx.x & 63;
    int row  = (blockIdx.x - 1412) * 4 + wid;
    const float* xr = x + (size_t)row * DIM;
    float2 xv = *(const float2*)(xr + lane * 2);
    float s = xv.x + xv.y, sq = xv.x * xv.x + xv.y * xv.y;
    #pragma unroll
    for (int off = 32; off > 0; off >>= 1) {
        s  += __shfl_down(s, off);
        sq += __shfl_down(sq, off);
    }
    s = __shfl(s, 0); sq = __shfl(sq, 0);
    float mu  = s * (1.0f / 128.0f);
    float var = sq * (1.0f / 128.0f) - mu * mu;
    float rs  = rsqrtf(var + 1e-5f);
    float2 gv = *(const float2*)(lng + lane * 2);
    float2 bv = *(const float2*)(lnb + lane * 2);
    float y0 = (xv.x - mu) * rs * gv.x + bv.x;
    float y1 = (xv.y - mu) * rs * gv.y + bv.y;
    u32 packed = (u32)(unsigned short)f2bs(y0) | ((u32)(unsigned short)f2bs(y1) << 16);
    *(u32*)(xa + (size_t)row * DIM + lane * 2) = packed;
    float4 w0 = *(const float4*)(wb + lane * 8);
    float4 w1v = *(const float4*)(wb + lane * 8 + 4);
    #pragma unroll
    for (int h = 0; h < NH; ++h) {
        float bh = xv.x * ((const float*)&w0)[h] + xv.y * ((const float*)&w1v)[h];
        #pragma unroll
        for (int off = 32; off > 0; off >>= 1) bh += __shfl_down(bh, off);
        if (lane == 0) bias[(size_t)h * MROWS + row] = bh;
    }
}

// ---------------- bf16 MFMA GEMM, BK=64, 32KB LDS, fused epilogues ---------------------
enum { EPI_QKVG = 0, EPI_OUT = 1 };

template<int EPI, int BM, int K>
__global__ __launch_bounds__(256, 4)
void mfma_gemm(const bf16* __restrict__ A, const bf16* __restrict__ BT,
               const float* __restrict__ e_bias,   // bg | bo
               const float* __restrict__ e_resid,  // -  | xin
               float* __restrict__ e_outf,         // -  | X
               bf16* __restrict__ e_outb,          // QKV| -
               bf16* __restrict__ e_outb2,         // Gb | -
               const float* __restrict__ lng,      // next-LN gamma (OUT)
               const float* __restrict__ lnb,      // next-LN beta  (OUT)
               const float* __restrict__ wbp,      // next-stage wb [128][4] (OUT1)
               float* __restrict__ biasb,          // next-stage bias out (OUT1)
               bf16* __restrict__ xa,              // next-LN output (OUT)
               int trans)
{
    constexpr int MREP  = BM / 32;
    constexpr int AB    = BM * 128;
    constexpr int STAGE = AB + 16384;
    constexpr int EPIB  = (BM / 2) * 512;
    constexpr int LDSB  = STAGE > EPIB ? STAGE : EPIB;
    __shared__ char sm[LDSB];
    char* asb = sm;
    char* bsb = sm + AB;
    float* eb = (float*)sm;

    int tid = threadIdx.x;
    int l = tid & 63, w = tid >> 6;
    int wr = w >> 1, wc = w & 1;
    int m0 = blockIdx.x * BM, n0 = blockIdx.y * 128;
    int fr = l & 15, g = l >> 4;
    int lr8 = l >> 3;
    int satom = (l & 7) ^ lr8;

    f32x4 acc[MREP][4] = {};

    for (int k0 = 0; k0 < K; k0 += 64) {
        #pragma unroll
        for (int i = 0; i < BM / 32; ++i)
            gload16(A + (size_t)(m0 + i * 32 + w * 8 + lr8) * K + k0 + satom * 8,
                    asb + i * 4096 + w * 1024);
        #pragma unroll
        for (int i = 0; i < 4; ++i)
            gload16(BT + (size_t)(n0 + i * 32 + w * 8 + lr8) * K + k0 + satom * 8,
                    bsb + i * 4096 + w * 1024);
        __syncthreads();
        #pragma unroll
        for (int kk = 0; kk < 2; ++kk) {
            bf16x8 af[MREP], bfr[4];
            #pragma unroll
            for (int mi = 0; mi < MREP; ++mi) {
                int r = wr * (BM / 2) + mi * 16 + fr;
                af[mi] = *(const bf16x8*)(asb + r * 128 + ((kk * 64 + g * 16) ^ ((r & 7) << 4)));
            }
            #pragma unroll
            for (int ni = 0; ni < 4; ++ni) {
                int r = wc * 64 + ni * 16 + fr;
                bfr[ni] = *(const bf16x8*)(bsb + r * 128 + ((kk * 64 + g * 16) ^ ((r & 7) << 4)));
            }
            #pragma unroll
            for (int mi = 0; mi < MREP; ++mi)
                #pragma unroll
                for (int ni = 0; ni < 4; ++ni)
                    acc[mi][ni] = __builtin_amdgcn_mfma_f32_16x16x32_bf16(
                        af[mi], bfr[ni], acc[mi][ni], 0, 0, 0);
        }
        __syncthreads();
    }

    // ---- epilogue: two half-tile rounds through LDS ----
    #pragma unroll
    for (int rr = 0; rr < 2; ++rr) {
        if (wr == rr) {
            #pragma unroll
            for (int mi = 0; mi < MREP; ++mi)
                #pragma unroll
                for (int ni = 0; ni < 4; ++ni)
                    #pragma unroll
                    for (int j = 0; j < 4; ++j) {
                        int rl = mi * 16 + g * 4 + j;
                        int cl = wc * 64 + ni * 16 + fr;
                        int a  = cl >> 2;
                        int pa = (((a >> 2) + (a & 3)) & 7) | ((a & 3) << 3);
                        eb[rl * 128 + pa * 4 + (cl & 3)] = acc[mi][ni][j];
                    }
        }
        __syncthreads();
        #pragma unroll
        for (int p = 0; p < BM / 64; ++p) {
            int c = tid + p * 256;
            int row_l = c >> 3, ch = c & 7;
            int grow = m0 + rr * (BM / 2) + row_l;
            int gc0 = ch * 16;
            float v[16];
            #pragma unroll
            for (int q = 0; q < 4; ++q) {
                int pa = ((ch + q) & 7) + q * 8;
                f32x4 t4 = *(const f32x4*)&eb[row_l * 128 + pa * 4];
                v[q * 4 + 0] = t4[0]; v[q * 4 + 1] = t4[1];
                v[q * 4 + 2] = t4[2]; v[q * 4 + 3] = t4[3];
            }
            if (EPI == EPI_QKVG) {
                int seg = blockIdx.y;
                short o16[16];
                if (seg < 3) {
                    #pragma unroll
                    for (int i = 0; i < 16; ++i) o16[i] = f2bs(v[i]);
                    int h = ch >> 1, e0 = (ch & 1) * 16;
                    bf16* dst = e_outb + ((size_t)(seg * NH + h) * MROWS + grow) * DHEAD + e0;
                    *(uint4*)dst = *(uint4*)o16;
                    *(uint4*)(dst + 8) = *(uint4*)(o16 + 8);
                } else {
                    #pragma unroll
                    for (int i = 0; i < 16; ++i)
                        o16[i] = f2bs(1.0f / (1.0f + __expf(-(v[i] + e_bias[gc0 + i]))));
                    bf16* dst = e_outb2 + (size_t)grow * DIM + gc0;
                    *(uint4*)dst = *(uint4*)o16;
                    *(uint4*)(dst + 8) = *(uint4*)(o16 + 8);
                }
            } else { // EPI_OUT
                int orow  = trans ? ((grow % NSEQ) * NSEQ + grow / NSEQ) : grow;
                int xarow = (grow % NSEQ) * NSEQ + grow / NSEQ;
                const float* rp = e_resid + (size_t)orow * DIM + gc0;
                float* op = e_outf + (size_t)orow * DIM + gc0;
                #pragma unroll
                for (int q = 0; q < 4; ++q) {
                    float4 r4 = *(const float4*)(rp + q * 4);
                    v[q*4+0] += e_bias[gc0 + q*4 + 0] + r4.x;
                    v[q*4+1] += e_bias[gc0 + q*4 + 1] + r4.y;
                    v[q*4+2] += e_bias[gc0 + q*4 + 2] + r4.z;
                    v[q*4+3] += e_bias[gc0 + q*4 + 3] + r4.w;
                    *(float4*)(op + q * 4) = make_float4(v[q*4+0], v[q*4+1], v[q*4+2], v[q*4+3]);
                }
                float s1 = 0.f, s2 = 0.f;
                #pragma unroll
                for (int i = 0; i < 16; ++i) { s1 += v[i]; s2 += v[i] * v[i]; }
                #pragma unroll
                for (int off = 1; off < 8; off <<= 1) {
                    s1 += __shfl_xor(s1, off);
                    s2 += __shfl_xor(s2, off);
                }
                float mu  = s1 * (1.0f / 128.0f);
                float var = s2 * (1.0f / 128.0f) - mu * mu;
                float rs  = rsqrtf(var + 1e-5f);
                short o16[16];
                #pragma unroll
                for (int i = 0; i < 16; ++i)
                    o16[i] = f2bs((v[i] - mu) * rs * lng[gc0 + i] + lnb[gc0 + i]);
                bf16* xd = xa + (size_t)xarow * DIM + gc0;
                *(uint4*)xd = *(uint4*)o16;
                *(uint4*)(xd + 8) = *(uint4*)(o16 + 8);
                if (wbp) {
                    float bh[NH] = {};
                    #pragma unroll
                    for (int i = 0; i < 16; ++i) {
                        float vv = v[i];
                        #pragma unroll
                        for (int h = 0; h < NH; ++h)
                            bh[h] = fmaf(vv, wbp[(gc0 + i) * NH + h], bh[h]);
                    }
                    #pragma unroll
                    for (int off = 1; off < 8; off <<= 1)
                        #pragma unroll
                        for (int h = 0; h < NH; ++h) bh[h] += __shfl_xor(bh[h], off);
                    if (ch == 0)
                        #pragma unroll
                        for (int h = 0; h < NH; ++h)
                            biasb[(size_t)h * MROWS + grow] = bh[h];
                }
            }
        }
        __syncthreads();
    }
}

// ---------------- Fused FFN: out = X + (geglu(XA@w1p+b1p)) @ w2 + b2 ------------------
// Block = 64 rows. Stream W1 in 8 chunks of 128 paired rows; GEGLU in-register;
// P chunk (64x64 bf16) through swizzled LDS; accumulate @W2 chunk; epilogue adds
// b2 + residual, writes f32 d_out. H2 never touches global memory.
__global__ __launch_bounds__(256, 2)
void ffn_kernel(const bf16* __restrict__ XA, const bf16* __restrict__ W1PT,
                const bf16* __restrict__ W2T, const float* __restrict__ B1P,
                const float* __restrict__ b2, const float* __restrict__ X,
                float* __restrict__ out)
{
    __shared__ char sm[73728];
    char* asb = sm;            // XA tile: 64 rows x 256B
    char* w1b = sm + 16384;    // W1 chunk: 128 rows x 256B
    char* pbuf = sm + 49152;   // P chunk: 64 rows x 128B
    char* w2b = sm + 57344;    // W2 chunk: 128 rows x 128B
    int tid = threadIdx.x;
    int l = tid & 63, w = tid >> 6;
    int wr = w >> 1, wc = w & 1;
    int fr = l & 15, g = l >> 4;
    int m0 = blockIdx.x * 64;

    {   // stage XA rows (256B rows: 16 rows/instr)
        int r16 = tid >> 4, a = tid & 15;
        int ap = a ^ (r16 & 7);
        #pragma unroll
        for (int i = 0; i < 4; ++i)
            gload16(XA + (size_t)(m0 + i * 16 + r16) * 128 + ap * 8,
                    asb + i * 4096 + w * 1024);
    }
    f32x4 acc2[2][4] = {};

    for (int c = 0; c < 8; ++c) {
        {   // stage W1 chunk rows c*128..+127
            int r16 = tid >> 4, a = tid & 15;
            int ap = a ^ (r16 & 7);
            #pragma unroll
            for (int i = 0; i < 8; ++i)
                gload16(W1PT + (size_t)(c * 128 + i * 16 + r16) * 128 + ap * 8,
                        w1b + i * 4096 + w * 1024);
        }
        __syncthreads();
        // chunk GEMM: acc1 = XA(64x128) @ W1c^T(128 paired-cols x 128)
        f32x4 acc1[2][4] = {};
        #pragma unroll
        for (int kk = 0; kk < 4; ++kk) {
            bf16x8 af[2], bfr[4];
            #pragma unroll
            for (int mi = 0; mi < 2; ++mi) {
                int r = wr * 32 + mi * 16 + fr;
                af[mi] = *(const bf16x8*)(asb + r * 256 + ((kk * 64 + g * 16) ^ ((r & 7) << 4)));
            }
            #pragma unroll
            for (int ni = 0; ni < 4; ++ni) {
                int r = wc * 64 + ni * 16 + fr;
                bfr[ni] = *(const bf16x8*)(w1b + r * 256 + ((kk * 64 + g * 16) ^ ((r & 7) << 4)));
            }
            #pragma unroll
            for (int mi = 0; mi < 2; ++mi)
                #pragma unroll
                for (int ni = 0; ni < 4; ++ni)
                    acc1[mi][ni] = __builtin_amdgcn_mfma_f32_16x16x32_bf16(
                        af[mi], bfr[ni], acc1[mi][ni], 0, 0, 0);
        }
        __syncthreads();
        // GEGLU -> P LDS (even paired-col lanes write bf16), stage W2 chunk
        #pragma unroll
        for (int mi = 0; mi < 2; ++mi)
            #pragma unroll
            for (int ni = 0; ni < 4; ++ni)
                #pragma unroll
                for (int j = 0; j < 4; ++j) {
                    int rl = wr * 32 + mi * 16 + g * 4 + j;
                    int cl = wc * 64 + ni * 16 + fr;
                    float v = acc1[mi][ni][j] + B1P[c * 128 + cl];
                    float pg = __shfl_xor(v, 1);
                    if (!(fr & 1)) {
                        float y  = 1.5957691216f * (pg + 0.044715f * pg * pg * pg);
                        float ge = pg / (1.0f + __expf(-y));
                        *(short*)(pbuf + rl * 128 + ((((cl >> 1) * 2)) ^ ((rl & 7) << 4)))
                            = f2bs(v * ge);
                    }
                }
        {   // stage W2 chunk: 128 rows x 64 k (128B rows: 32 rows/instr)
            int r32 = tid >> 3, a = tid & 7;
            int ap = a ^ (r32 & 7);
            #pragma unroll
            for (int i = 0; i < 4; ++i)
                gload16(W2T + (size_t)(i * 32 + r32) * 512 + c * 64 + ap * 8,
                        w2b + i * 4096 + w * 1024);
        }
        __syncthreads();
        // FF2 accumulate: acc2 += P(64x64) @ W2c^T(128x64)
        #pragma unroll
        for (int kk = 0; kk < 2; ++kk) {
            bf16x8 pf[2], bfr[4];
            #pragma unroll
            for (int mi = 0; mi < 2; ++mi) {
                int r = wr * 32 + mi * 16 + fr;
                pf[mi] = *(const bf16x8*)(pbuf + r * 128 + ((kk * 64 + g * 16) ^ ((r & 7) << 4)));
            }
            #pragma unroll
            for (int ni = 0; ni < 4; ++ni) {
                int r = wc * 64 + ni * 16 + fr;
                bfr[ni] = *(const bf16x8*)(w2b + r * 128 + ((kk * 64 + g * 16) ^ ((r & 7) << 4)));
            }
            #pragma unroll
            for (int mi = 0; mi < 2; ++mi)
                #pragma unroll
                for (int ni = 0; ni < 4; ++ni)
                    acc2[mi][ni] = __builtin_amdgcn_mfma_f32_16x16x32_bf16(
                        pf[mi], bfr[ni], acc2[mi][ni], 0, 0, 0);
        }
        __syncthreads();
    }
    // epilogue: + b2 + residual, f32 out
    #pragma unroll
    for (int mi = 0; mi < 2; ++mi)
        #pragma unroll
        for (int ni = 0; ni < 4; ++ni)
            #pragma unroll
            for (int j = 0; j < 4; ++j) {
                int row = m0 + wr * 32 + mi * 16 + g * 4 + j;
                int col = wc * 64 + ni * 16 + fr;
                out[(size_t)row * DIM + col] =
                    acc2[mi][ni][j] + b2[col] + X[(size_t)row * DIM + col];
            }
}

// ---------------- MFMA flash attention: block=(h,r), 4 waves x 48 q-rows ---------------
__global__ __launch_bounds__(256)
void attn_mfma_kernel(const bf16* __restrict__ Qh, const bf16* __restrict__ Kh,
                      const bf16* __restrict__ Vh, const float* __restrict__ BIAS,
                      const bf16* __restrict__ G, bf16* __restrict__ TMP)
{
    __shared__ unsigned short vtp[32][200];   // V^T permuted, row stride 400B (16B mult)
    int h = blockIdx.x / NSEQ;
    int r = blockIdx.x % NSEQ;
    int t = threadIdx.x;
    int l = t & 63;
    int w = t >> 6;

    const bf16* vbase = Vh + ((size_t)h * MROWS + (size_t)r * NSEQ) * DHEAD;
    #pragma unroll
    for (int i = 0; i < 6; ++i) {
        int q4 = t + i * 256;                 // 1536 quads
        int k = q4 >> 3, e0 = (q4 & 7) * 4;
        uint2 v = *(const uint2*)(vbase + (size_t)k * DHEAD + e0);
        int kk = k & 31, sup = k >> 5;
        int col = sup * 32 + ((kk & 15) >> 2) * 8 + (kk & 3) + ((kk >> 4) << 2);
        const unsigned short* vs = (const unsigned short*)&v;
        #pragma unroll
        for (int j = 0; j < 4; ++j) vtp[e0 + j][col] = vs[j];
    }
    __syncthreads();

    int fr = l & 15, g = l >> 4;
    int q0 = w * 48;
    const bf16*  qbase = Qh + ((size_t)h * MROWS + (size_t)r * NSEQ) * DHEAD;
    const bf16*  kbase = Kh + ((size_t)h * MROWS + (size_t)r * NSEQ) * DHEAD;
    const float* bbase = BIAS + (size_t)h * MROWS;

    bf16x8 qf[3];
    #pragma unroll
    for (int i = 0; i < 3; ++i)
        qf[i] = *(const bf16x8*)(qbase + (size_t)(q0 + i * 16 + fr) * DHEAD + g * 8);

    f32x4 ot[3][2] = {};
    float m_[3] = {-1e30f, -1e30f, -1e30f};
    float s_[3] = {};

    for (int sup = 0; sup < 6; ++sup) {
        bf16x8 kf0 = *(const bf16x8*)(kbase + (size_t)(sup * 32 + fr) * DHEAD + g * 8);
        bf16x8 kf1 = *(const bf16x8*)(kbase + (size_t)(sup * 32 + 16 + fr) * DHEAD + g * 8);
        bf16x8 pb[3];
        #pragma unroll
        for (int qt = 0; qt < 3; ++qt) {
            f32x4 z = {};
            f32x4 s0 = __builtin_amdgcn_mfma_f32_16x16x32_bf16(kf0, qf[qt], z, 0, 0, 0);
            f32x4 s1 = __builtin_amdgcn_mfma_f32_16x16x32_bf16(kf1, qf[qt], z, 0, 0, 0);
            const float* bp = bbase + (size_t)(q0 + qt * 16 + fr) * NSEQ + sup * 32 + g * 4;
            float4 b0 = *(const float4*)bp;
            float4 b1 = *(const float4*)(bp + 16);
            s0[0] += b0.x; s0[1] += b0.y; s0[2] += b0.z; s0[3] += b0.w;
            s1[0] += b1.x; s1[1] += b1.y; s1[2] += b1.z; s1[3] += b1.w;
            float tmax = fmaxf(fmaxf(fmaxf(s0[0], s0[1]), fmaxf(s0[2], s0[3])),
                               fmaxf(fmaxf(s1[0], s1[1]), fmaxf(s1[2], s1[3])));
            tmax = fmaxf(tmax, __shfl_xor(tmax, 16));
            tmax = fmaxf(tmax, __shfl_xor(tmax, 32));
            if (__any(tmax > m_[qt] + 8.0f)) {       // defer-max (T13)
                float mn = fmaxf(m_[qt], tmax);
                float c = __expf(m_[qt] - mn);
                s_[qt] *= c; ot[qt][0] *= c; ot[qt][1] *= c;
                m_[qt] = mn;
            }
            float p[8];
            #pragma unroll
            for (int j = 0; j < 4; ++j) p[j]     = __expf(s0[j] - m_[qt]);
            #pragma unroll
            for (int j = 0; j < 4; ++j) p[4 + j] = __expf(s1[j] - m_[qt]);
            s_[qt] += ((p[0] + p[1]) + (p[2] + p[3])) + ((p[4] + p[5]) + (p[6] + p[7]));
            bf16x8 pk;
            #pragma unroll
            for (int j = 0; j < 8; ++j) pk[j] = f2bs(p[j]);
            pb[qt] = pk;
        }
        #pragma unroll
        for (int et = 0; et < 2; ++et) {
            bf16x8 vf = *(const bf16x8*)(&vtp[et * 16 + fr][sup * 32 + g * 8]);
            #pragma unroll
            for (int qt = 0; qt < 3; ++qt)
                ot[qt][et] = __builtin_amdgcn_mfma_f32_16x16x32_bf16(vf, pb[qt], ot[qt][et], 0, 0, 0);
        }
    }

    #pragma unroll
    for (int qt = 0; qt < 3; ++qt) {
        float sq = s_[qt];
        sq += __shfl_xor(sq, 16);
        sq += __shfl_xor(sq, 32);
        float inv = 1.0f / sq;
        int q = q0 + qt * 16 + fr;
        size_t row = (size_t)r * NSEQ + q;
        #pragma unroll
        for (int et = 0; et < 2; ++et) {
            int e0 = h * DHEAD + et * 16 + g * 4;
            const bf16* gp = G + row * DIM + e0;
            u32 g01 = *(const u32*)gp;
            u32 g23 = *(const u32*)(gp + 2);
            float gx0 = __uint_as_float((g01 & 0xffffu) << 16);
            float gx1 = __uint_as_float(g01 & 0xffff0000u);
            float gx2 = __uint_as_float((g23 & 0xffffu) << 16);
            float gx3 = __uint_as_float(g23 & 0xffff0000u);
            short o4[4];
            o4[0] = f2bs(ot[qt][et][0] * inv * gx0);
            o4[1] = f2bs(ot[qt][et][1] * inv * gx1);
            o4[2] = f2bs(ot[qt][et][2] * inv * gx2);
            o4[3] = f2bs(ot[qt][et][3] * inv * gx3);
            *(uint2*)(TMP + row * DIM + e0) = *(uint2*)o4;
        }
    }
}

extern "C" void kernel_launch(void* const* d_in, const int* in_sizes, int n_in,
                              void* d_out, int out_size, void* d_ws, size_t ws_size,
                              hipStream_t stream) {
    const float* x     = (const float*)d_in[0];
    const float* lng_o = (const float*)d_in[1];
    const float* lnb_o = (const float*)d_in[2];
    const float* wq_o  = (const float*)d_in[3];
    const float* wkv_o = (const float*)d_in[4];
    const float* wo_o  = (const float*)d_in[5];
    const float* bo_o  = (const float*)d_in[6];
    const float* wg_o  = (const float*)d_in[7];
    const float* bg_o  = (const float*)d_in[8];
    const float* wb_o  = (const float*)d_in[9];
    const float* lng_i = (const float*)d_in[10];
    const float* lnb_i = (const float*)d_in[11];
    const float* wq_i  = (const float*)d_in[12];
    const float* wkv_i = (const float*)d_in[13];
    const float* wo_i  = (const float*)d_in[14];
    const float* bo_i  = (const float*)d_in[15];
    const float* wg_i  = (const float*)d_in[16];
    const float* bg_i  = (const float*)d_in[17];
    const float* wb_i  = (const float*)d_in[18];
    const float* lng_f = (const float*)d_in[19];
    const float* lnb_f = (const float*)d_in[20];
    const float* w1    = (const float*)d_in[21];
    const float* b1    = (const float*)d_in[22];
    const float* w2    = (const float*)d_in[23];
    const float* b2    = (const float*)d_in[24];

    const size_t T = (size_t)MROWS * DIM;
    char* base = (char*)d_ws;
    bf16*  XA    = (bf16*)base;  base += T * 2;            // bf16 LN output
    float* X     = (float*)base; base += T * 4;            // f32 running residual
    bf16*  QKVb  = (bf16*)base;  base += 3 * T * 2;        // Q,K,V bf16 [3][4][MROWS][32]
    bf16*  Gb    = (bf16*)base;  base += T * 2;            // gate bf16 [MROWS][128]
    float* BIASb = (float*)base; base += (size_t)NH * MROWS * 4;
    bf16*  TMP   = (bf16*)base;  base += T * 2;            // o*gates bf16
    bf16*  WQKVG_O = (bf16*)base; base += 512 * 128 * 2;
    bf16*  WQKVG_I = (bf16*)base; base += 512 * 128 * 2;
    bf16*  WOT_O   = (bf16*)base; base += 128 * 128 * 2;
    bf16*  WOT_I   = (bf16*)base; base += 128 * 128 * 2;
    bf16*  W1PT    = (bf16*)base; base += 1024 * 128 * 2;
    bf16*  W2T     = (bf16*)base; base += 128 * 512 * 2;
    float* B1P     = (float*)base; base += 1024 * 4;
    bf16*  Qhp = QKVb;
    bf16*  Khp = QKVb + T;
    bf16*  Vhp = QKVb + 2 * T;

    // prep: weight convert (blocks 0..1411) + LN1 + bias-projection (blocks 1412..)
    prep_kernel<<<1412 + MROWS / 4, 256, 0, stream>>>(
        wq_o, wkv_o, wg_o, wq_i, wkv_i, wg_i, wo_o, wo_i, w1, b1, w2,
        WQKVG_O, WQKVG_I, WOT_O, WOT_I, W1PT, W2T, B1P,
        x, lng_o, lnb_o, wb_o, XA, BIASb);

    dim3 gQKVG(MROWS / 128, 4), gOUT(MROWS / 128, 1);

    // ---- stage 1: row attention, x -> X (OUT fuses LN2 + stage-2 bias proj) ----
    mfma_gemm<EPI_QKVG, 128, 128><<<gQKVG, 256, 0, stream>>>(
        XA, WQKVG_O, bg_o, nullptr, nullptr, QKVb, Gb,
        nullptr, nullptr, nullptr, nullptr, nullptr, 0);
    attn_mfma_kernel<<<NSEQ * NH, 256, 0, stream>>>(Qhp, Khp, Vhp, BIASb, Gb, TMP);
    mfma_gemm<EPI_OUT, 128, 128><<<gOUT, 256, 0, stream>>>(
        TMP, WOT_O, bo_o, x, X, nullptr, nullptr,
        lng_i, lnb_i, wb_i, BIASb, XA, 0);

    // ---- stage 2: col attention, X -> X in place (OUT fuses final LN) ----
    mfma_gemm<EPI_QKVG, 128, 128><<<gQKVG, 256, 0, stream>>>(
        XA, WQKVG_I, bg_i, nullptr, nullptr, QKVb, Gb,
        nullptr, nullptr, nullptr, nullptr, nullptr, 0);
    attn_mfma_kernel<<<NSEQ * NH, 256, 0, stream>>>(Qhp, Khp, Vhp, BIASb, Gb, TMP);
    mfma_gemm<EPI_OUT, 128, 128><<<gOUT, 256, 0, stream>>>(
        TMP, WOT_I, bo_i, X, X, nullptr, nullptr,
        lng_f, lnb_f, nullptr, nullptr, XA, 1);

    // ---- FFN fused: out = X + geglu(XA@w1p+b1p)@w2 + b2 ----
    ffn_kernel<<<MROWS / 64, 256, 0, stream>>>(XA, W1PT, W2T, B1P, b2, X, (float*)d_out);
}

// Round 7
// 193.013 us; speedup vs baseline: 1.4094x; 1.4094x over previous
//
#include <hip/hip_runtime.h>
#include <hip/hip_bf16.h>
#include <math.h>

constexpr int NSEQ = 192;
constexpr int DIM  = 128;
constexpr int NH   = 4;
constexpr int DHEAD = 32;
constexpr int MROWS = NSEQ * NSEQ; // 36864

typedef __hip_bfloat16 bf16;
typedef __attribute__((ext_vector_type(8))) short bf16x8;
typedef __attribute__((ext_vector_type(4))) float f32x4;
typedef unsigned int u32;

__device__ __forceinline__ void gload16(const void* g, void* l) {
    __builtin_amdgcn_global_load_lds(
        (const __attribute__((address_space(1))) u32*)g,
        (__attribute__((address_space(3))) u32*)l, 16, 0, 0);
}

__device__ __forceinline__ short f2bs(float f) {
    __hip_bfloat16 h = __float2bfloat16(f);
    return *(short*)&h;
}
__device__ __forceinline__ float bs2f(unsigned short s) {
    return __uint_as_float(((u32)s) << 16);
}

// ---------------- prep: weight convert (blocks 0..1411) + LN1+biasproj+x->bf16 ---------
__global__ __launch_bounds__(256)
void prep_kernel(const float* __restrict__ wq_o, const float* __restrict__ wkv_o,
                 const float* __restrict__ wg_o,
                 const float* __restrict__ wq_i, const float* __restrict__ wkv_i,
                 const float* __restrict__ wg_i,
                 const float* __restrict__ wo_o, const float* __restrict__ wo_i,
                 const float* __restrict__ w1, const float* __restrict__ b1,
                 const float* __restrict__ w2,
                 bf16* __restrict__ WQKVG_O, bf16* __restrict__ WQKVG_I,
                 bf16* __restrict__ WOT_O, bf16* __restrict__ WOT_I,
                 bf16* __restrict__ W1PT, bf16* __restrict__ W2T,
                 float* __restrict__ B1P,
                 const float* __restrict__ x, const float* __restrict__ lng,
                 const float* __restrict__ lnb, const float* __restrict__ wb,
                 bf16* __restrict__ xa, float* __restrict__ bias,
                 bf16* __restrict__ xb)
{
    if (blockIdx.x < 1412) {
        int idx = blockIdx.x * 256 + threadIdx.x;
        const float scale = 0.17677669529663689f; // 32^-0.5 folded into wq
        if (idx < 131072) {                       // WQKVG_{o,i}: [512][128], rows q|k|v|g
            int s = idx >> 16, i = idx & 65535;
            int r = i >> 7, d = i & 127;
            const float* wq  = s ? wq_i  : wq_o;
            const float* wkv = s ? wkv_i : wkv_o;
            const float* wg  = s ? wg_i  : wg_o;
            float v;
            if (r < 128)      v = wq[d * 128 + r] * scale;
            else if (r < 384) v = wkv[d * 256 + (r - 128)];
            else              v = wg[d * 128 + (r - 384)];
            (s ? WQKVG_I : WQKVG_O)[i] = __float2bfloat16(v);
        } else if (idx < 163840) {                // WOT_{o,i}: [128][128] = wo^T
            int i = idx - 131072; int s = i >> 14; i &= 16383;
            int r = i >> 7, d = i & 127;
            (s ? WOT_I : WOT_O)[i] = __float2bfloat16((s ? wo_i : wo_o)[d * 128 + r]);
        } else if (idx < 294912) {                // W1PT: [1024][128], rows 2j=a_j, 2j+1=g_j
            int i = idx - 163840;
            int r = i >> 7, d = i & 127;
            int col = (r & 1) ? 512 + (r >> 1) : (r >> 1);
            W1PT[i] = __float2bfloat16(w1[d * 1024 + col]);
        } else if (idx < 360448) {                // W2T: [128][512] = w2^T
            int i = idx - 294912;
            int n = i >> 9, k = i & 511;
            W2T[i] = __float2bfloat16(w2[k * 128 + n]);
        } else if (idx < 361472) {                // B1P: paired bias
            int r = idx - 360448;
            B1P[r] = b1[(r & 1) ? 512 + (r >> 1) : (r >> 1)];
        }
        return;
    }
    // ---- LN1 + bias projection + x->bf16 copy (lane owns elems 2l, 2l+1) ----
    int wid  = threadIdx.x >> 6;
    int lane = threadIdx.x & 63;
    int row  = (blockIdx.x - 1412) * 4 + wid;
    const float* xr = x + (size_t)row * DIM;
    float2 xv = *(const float2*)(xr + lane * 2);
    float s = xv.x + xv.y, sq = xv.x * xv.x + xv.y * xv.y;
    #pragma unroll
    for (int off = 32; off > 0; off >>= 1) {
        s  += __shfl_down(s, off);
        sq += __shfl_down(sq, off);
    }
    s = __shfl(s, 0); sq = __shfl(sq, 0);
    float mu  = s * (1.0f / 128.0f);
    float var = sq * (1.0f / 128.0f) - mu * mu;
    float rs  = rsqrtf(var + 1e-5f);
    float2 gv = *(const float2*)(lng + lane * 2);
    float2 bv = *(const float2*)(lnb + lane * 2);
    float y0 = (xv.x - mu) * rs * gv.x + bv.x;
    float y1 = (xv.y - mu) * rs * gv.y + bv.y;
    u32 packed = (u32)(unsigned short)f2bs(y0) | ((u32)(unsigned short)f2bs(y1) << 16);
    *(u32*)(xa + (size_t)row * DIM + lane * 2) = packed;
    u32 packedx = (u32)(unsigned short)f2bs(xv.x) | ((u32)(unsigned short)f2bs(xv.y) << 16);
    *(u32*)(xb + (size_t)row * DIM + lane * 2) = packedx;
    float4 w0 = *(const float4*)(wb + lane * 8);
    float4 w1v = *(const float4*)(wb + lane * 8 + 4);
    #pragma unroll
    for (int h = 0; h < NH; ++h) {
        float bh = xv.x * ((const float*)&w0)[h] + xv.y * ((const float*)&w1v)[h];
        #pragma unroll
        for (int off = 32; off > 0; off >>= 1) bh += __shfl_down(bh, off);
        if (lane == 0) bias[(size_t)h * MROWS + row] = bh;
    }
}

// ---------------- bf16 MFMA GEMM, BK=64, fused epilogues -------------------------------
enum { EPI_QKVG = 0, EPI_OUT = 1, EPI_GEGLU = 2, EPI_FF2 = 3 };

template<int EPI, int BM, int K>
__global__ __launch_bounds__(256, 4)
void mfma_gemm(const bf16* __restrict__ A, const bf16* __restrict__ BT,
               const float* __restrict__ e_bias,   // bg | bo | b1p | b2
               const bf16* __restrict__ e_residb,  // -  | xin(bf16) | - | X(bf16)
               float* __restrict__ e_outf,         // -  | -   | -   | out (f32)
               bf16* __restrict__ e_outb,          // QKV| Xout| H2  | -
               bf16* __restrict__ e_outb2,         // Gb | -   | -   | -
               const float* __restrict__ lng,      // next-LN gamma (OUT)
               const float* __restrict__ lnb,      // next-LN beta  (OUT)
               const float* __restrict__ wbp,      // next-stage wb [128][4] (OUT1)
               float* __restrict__ biasb,          // next-stage bias out (OUT1)
               bf16* __restrict__ xa,              // next-LN output (OUT)
               int trans)
{
    constexpr int MREP  = BM / 32;
    constexpr int AB    = BM * 128;
    constexpr int STAGE = AB + 16384;
    constexpr int EPIB  = (BM / 2) * 512;
    constexpr int LDSB  = STAGE > EPIB ? STAGE : EPIB;
    __shared__ char sm[LDSB];
    char* asb = sm;
    char* bsb = sm + AB;
    float* eb = (float*)sm;

    int tid = threadIdx.x;
    int l = tid & 63, w = tid >> 6;
    int wr = w >> 1, wc = w & 1;
    int m0 = blockIdx.x * BM, n0 = blockIdx.y * 128;
    int fr = l & 15, g = l >> 4;
    int lr8 = l >> 3;
    int satom = (l & 7) ^ lr8;

    f32x4 acc[MREP][4] = {};

    for (int k0 = 0; k0 < K; k0 += 64) {
        #pragma unroll
        for (int i = 0; i < BM / 32; ++i)
            gload16(A + (size_t)(m0 + i * 32 + w * 8 + lr8) * K + k0 + satom * 8,
                    asb + i * 4096 + w * 1024);
        #pragma unroll
        for (int i = 0; i < 4; ++i)
            gload16(BT + (size_t)(n0 + i * 32 + w * 8 + lr8) * K + k0 + satom * 8,
                    bsb + i * 4096 + w * 1024);
        __syncthreads();
        #pragma unroll
        for (int kk = 0; kk < 2; ++kk) {
            bf16x8 af[MREP], bfr[4];
            #pragma unroll
            for (int mi = 0; mi < MREP; ++mi) {
                int r = wr * (BM / 2) + mi * 16 + fr;
                af[mi] = *(const bf16x8*)(asb + r * 128 + ((kk * 64 + g * 16) ^ ((r & 7) << 4)));
            }
            #pragma unroll
            for (int ni = 0; ni < 4; ++ni) {
                int r = wc * 64 + ni * 16 + fr;
                bfr[ni] = *(const bf16x8*)(bsb + r * 128 + ((kk * 64 + g * 16) ^ ((r & 7) << 4)));
            }
            #pragma unroll
            for (int mi = 0; mi < MREP; ++mi)
                #pragma unroll
                for (int ni = 0; ni < 4; ++ni)
                    acc[mi][ni] = __builtin_amdgcn_mfma_f32_16x16x32_bf16(
                        af[mi], bfr[ni], acc[mi][ni], 0, 0, 0);
        }
        __syncthreads();
    }

    // ---- epilogue: two half-tile rounds through LDS (bijective atom perm) ----
    #pragma unroll
    for (int rr = 0; rr < 2; ++rr) {
        if (wr == rr) {
            #pragma unroll
            for (int mi = 0; mi < MREP; ++mi)
                #pragma unroll
                for (int ni = 0; ni < 4; ++ni)
                    #pragma unroll
                    for (int j = 0; j < 4; ++j) {
                        int rl = mi * 16 + g * 4 + j;
                        int cl = wc * 64 + ni * 16 + fr;
                        int a  = cl >> 2;
                        int pa = (((a >> 2) + (a & 3)) & 7) | ((a & 3) << 3);
                        eb[rl * 128 + pa * 4 + (cl & 3)] = acc[mi][ni][j];
                    }
        }
        __syncthreads();
        #pragma unroll
        for (int p = 0; p < BM / 64; ++p) {
            int c = tid + p * 256;
            int row_l = c >> 3, ch = c & 7;
            int grow = m0 + rr * (BM / 2) + row_l;
            int gc0 = ch * 16;
            float v[16];
            #pragma unroll
            for (int q = 0; q < 4; ++q) {
                int pa = ((ch + q) & 7) + q * 8;
                f32x4 t4 = *(const f32x4*)&eb[row_l * 128 + pa * 4];
                v[q * 4 + 0] = t4[0]; v[q * 4 + 1] = t4[1];
                v[q * 4 + 2] = t4[2]; v[q * 4 + 3] = t4[3];
            }
            if (EPI == EPI_QKVG) {
                int seg = blockIdx.y;
                short o16[16];
                if (seg < 3) {
                    #pragma unroll
                    for (int i = 0; i < 16; ++i) o16[i] = f2bs(v[i]);
                    int h = ch >> 1, e0 = (ch & 1) * 16;
                    bf16* dst = e_outb + ((size_t)(seg * NH + h) * MROWS + grow) * DHEAD + e0;
                    *(uint4*)dst = *(uint4*)o16;
                    *(uint4*)(dst + 8) = *(uint4*)(o16 + 8);
                } else {
                    #pragma unroll
                    for (int i = 0; i < 16; ++i)
                        o16[i] = f2bs(1.0f / (1.0f + __expf(-(v[i] + e_bias[gc0 + i]))));
                    bf16* dst = e_outb2 + (size_t)grow * DIM + gc0;
                    *(uint4*)dst = *(uint4*)o16;
                    *(uint4*)(dst + 8) = *(uint4*)(o16 + 8);
                }
            } else if (EPI == EPI_OUT) {
                int orow  = trans ? ((grow % NSEQ) * NSEQ + grow / NSEQ) : grow;
                int xarow = (grow % NSEQ) * NSEQ + grow / NSEQ;
                unsigned short r16[16];
                const bf16* rp = e_residb + (size_t)orow * DIM + gc0;
                *(uint4*)r16 = *(const uint4*)rp;
                *(uint4*)(r16 + 8) = *(const uint4*)(rp + 8);
                short o16[16];
                #pragma unroll
                for (int i = 0; i < 16; ++i) {
                    v[i] += e_bias[gc0 + i] + bs2f(r16[i]);
                    o16[i] = f2bs(v[i]);
                }
                bf16* xo = e_outb + (size_t)orow * DIM + gc0;   // new residual X (bf16)
                *(uint4*)xo = *(uint4*)o16;
                *(uint4*)(xo + 8) = *(uint4*)(o16 + 8);
                float s1 = 0.f, s2 = 0.f;
                #pragma unroll
                for (int i = 0; i < 16; ++i) { s1 += v[i]; s2 += v[i] * v[i]; }
                #pragma unroll
                for (int off = 1; off < 8; off <<= 1) {
                    s1 += __shfl_xor(s1, off);
                    s2 += __shfl_xor(s2, off);
                }
                float mu  = s1 * (1.0f / 128.0f);
                float var = s2 * (1.0f / 128.0f) - mu * mu;
                float rs  = rsqrtf(var + 1e-5f);
                #pragma unroll
                for (int i = 0; i < 16; ++i)
                    o16[i] = f2bs((v[i] - mu) * rs * lng[gc0 + i] + lnb[gc0 + i]);
                bf16* xd = xa + (size_t)xarow * DIM + gc0;
                *(uint4*)xd = *(uint4*)o16;
                *(uint4*)(xd + 8) = *(uint4*)(o16 + 8);
                if (wbp) {
                    float bh[NH] = {};
                    #pragma unroll
                    for (int i = 0; i < 16; ++i) {
                        float vv = v[i];
                        #pragma unroll
                        for (int h = 0; h < NH; ++h)
                            bh[h] = fmaf(vv, wbp[(gc0 + i) * NH + h], bh[h]);
                    }
                    #pragma unroll
                    for (int off = 1; off < 8; off <<= 1)
                        #pragma unroll
                        for (int h = 0; h < NH; ++h) bh[h] += __shfl_xor(bh[h], off);
                    if (ch == 0)
                        #pragma unroll
                        for (int h = 0; h < NH; ++h)
                            biasb[(size_t)h * MROWS + grow] = bh[h];
                }
            } else if (EPI == EPI_FF2) {
                unsigned short r16[16];
                const bf16* rp = e_residb + (size_t)grow * DIM + gc0;
                *(uint4*)r16 = *(const uint4*)rp;
                *(uint4*)(r16 + 8) = *(const uint4*)(rp + 8);
                float* op = e_outf + (size_t)grow * DIM + gc0;
                #pragma unroll
                for (int q = 0; q < 4; ++q) {
                    float4 o4;
                    o4.x = v[q*4+0] + e_bias[gc0 + q*4 + 0] + bs2f(r16[q*4+0]);
                    o4.y = v[q*4+1] + e_bias[gc0 + q*4 + 1] + bs2f(r16[q*4+1]);
                    o4.z = v[q*4+2] + e_bias[gc0 + q*4 + 2] + bs2f(r16[q*4+2]);
                    o4.w = v[q*4+3] + e_bias[gc0 + q*4 + 3] + bs2f(r16[q*4+3]);
                    *(float4*)(op + q * 4) = o4;
                }
            } else { // EPI_GEGLU
                short o8[8];
                #pragma unroll
                for (int t = 0; t < 8; ++t) {
                    float a  = v[2*t]     + e_bias[n0 + gc0 + 2*t];
                    float gg = v[2*t + 1] + e_bias[n0 + gc0 + 2*t + 1];
                    float y  = 1.5957691216f * (gg + 0.044715f * gg * gg * gg);
                    float ge = gg / (1.0f + __expf(-y));   // tanh-form GELU
                    o8[t] = f2bs(a * ge);
                }
                *(uint4*)(e_outb + (size_t)grow * 512 + ((n0 + gc0) >> 1)) = *(uint4*)o8;
            }
        }
        __syncthreads();
    }
}

// ---------------- MFMA flash attention: block=(h,r), 4 waves x 48 q-rows ---------------
__global__ __launch_bounds__(256)
void attn_mfma_kernel(const bf16* __restrict__ Qh, const bf16* __restrict__ Kh,
                      const bf16* __restrict__ Vh, const float* __restrict__ BIAS,
                      const bf16* __restrict__ G, bf16* __restrict__ TMP)
{
    __shared__ unsigned short vtp[32][200];   // V^T permuted, row stride 400B (16B mult)
    int h = blockIdx.x / NSEQ;
    int r = blockIdx.x % NSEQ;
    int t = threadIdx.x;
    int l = t & 63;
    int w = t >> 6;

    const bf16* vbase = Vh + ((size_t)h * MROWS + (size_t)r * NSEQ) * DHEAD;
    #pragma unroll
    for (int i = 0; i < 6; ++i) {
        int q4 = t + i * 256;                 // 1536 quads
        int k = q4 >> 3, e0 = (q4 & 7) * 4;
        uint2 v = *(const uint2*)(vbase + (size_t)k * DHEAD + e0);
        int kk = k & 31, sup = k >> 5;
        int col = sup * 32 + ((kk & 15) >> 2) * 8 + (kk & 3) + ((kk >> 4) << 2);
        const unsigned short* vs = (const unsigned short*)&v;
        #pragma unroll
        for (int j = 0; j < 4; ++j) vtp[e0 + j][col] = vs[j];
    }
    __syncthreads();

    int fr = l & 15, g = l >> 4;
    int q0 = w * 48;
    const bf16*  qbase = Qh + ((size_t)h * MROWS + (size_t)r * NSEQ) * DHEAD;
    const bf16*  kbase = Kh + ((size_t)h * MROWS + (size_t)r * NSEQ) * DHEAD;
    const float* bbase = BIAS + (size_t)h * MROWS;

    bf16x8 qf[3];
    #pragma unroll
    for (int i = 0; i < 3; ++i)
        qf[i] = *(const bf16x8*)(qbase + (size_t)(q0 + i * 16 + fr) * DHEAD + g * 8);

    f32x4 ot[3][2] = {};
    float m_[3] = {-1e30f, -1e30f, -1e30f};
    float s_[3] = {};

    for (int sup = 0; sup < 6; ++sup) {
        bf16x8 kf0 = *(const bf16x8*)(kbase + (size_t)(sup * 32 + fr) * DHEAD + g * 8);
        bf16x8 kf1 = *(const bf16x8*)(kbase + (size_t)(sup * 32 + 16 + fr) * DHEAD + g * 8);
        bf16x8 pb[3];
        #pragma unroll
        for (int qt = 0; qt < 3; ++qt) {
            f32x4 z = {};
            f32x4 s0 = __builtin_amdgcn_mfma_f32_16x16x32_bf16(kf0, qf[qt], z, 0, 0, 0);
            f32x4 s1 = __builtin_amdgcn_mfma_f32_16x16x32_bf16(kf1, qf[qt], z, 0, 0, 0);
            const float* bp = bbase + (size_t)(q0 + qt * 16 + fr) * NSEQ + sup * 32 + g * 4;
            float4 b0 = *(const float4*)bp;
            float4 b1 = *(const float4*)(bp + 16);
            s0[0] += b0.x; s0[1] += b0.y; s0[2] += b0.z; s0[3] += b0.w;
            s1[0] += b1.x; s1[1] += b1.y; s1[2] += b1.z; s1[3] += b1.w;
            float tmax = fmaxf(fmaxf(fmaxf(s0[0], s0[1]), fmaxf(s0[2], s0[3])),
                               fmaxf(fmaxf(s1[0], s1[1]), fmaxf(s1[2], s1[3])));
            tmax = fmaxf(tmax, __shfl_xor(tmax, 16));
            tmax = fmaxf(tmax, __shfl_xor(tmax, 32));
            if (__any(tmax > m_[qt] + 8.0f)) {       // defer-max (T13)
                float mn = fmaxf(m_[qt], tmax);
                float c = __expf(m_[qt] - mn);
                s_[qt] *= c; ot[qt][0] *= c; ot[qt][1] *= c;
                m_[qt] = mn;
            }
            float p[8];
            #pragma unroll
            for (int j = 0; j < 4; ++j) p[j]     = __expf(s0[j] - m_[qt]);
            #pragma unroll
            for (int j = 0; j < 4; ++j) p[4 + j] = __expf(s1[j] - m_[qt]);
            s_[qt] += ((p[0] + p[1]) + (p[2] + p[3])) + ((p[4] + p[5]) + (p[6] + p[7]));
            bf16x8 pk;
            #pragma unroll
            for (int j = 0; j < 8; ++j) pk[j] = f2bs(p[j]);
            pb[qt] = pk;
        }
        #pragma unroll
        for (int et = 0; et < 2; ++et) {
            bf16x8 vf = *(const bf16x8*)(&vtp[et * 16 + fr][sup * 32 + g * 8]);
            #pragma unroll
            for (int qt = 0; qt < 3; ++qt)
                ot[qt][et] = __builtin_amdgcn_mfma_f32_16x16x32_bf16(vf, pb[qt], ot[qt][et], 0, 0, 0);
        }
    }

    #pragma unroll
    for (int qt = 0; qt < 3; ++qt) {
        float sq = s_[qt];
        sq += __shfl_xor(sq, 16);
        sq += __shfl_xor(sq, 32);
        float inv = 1.0f / sq;
        int q = q0 + qt * 16 + fr;
        size_t row = (size_t)r * NSEQ + q;
        #pragma unroll
        for (int et = 0; et < 2; ++et) {
            int e0 = h * DHEAD + et * 16 + g * 4;
            const bf16* gp = G + row * DIM + e0;
            u32 g01 = *(const u32*)gp;
            u32 g23 = *(const u32*)(gp + 2);
            float gx0 = __uint_as_float((g01 & 0xffffu) << 16);
            float gx1 = __uint_as_float(g01 & 0xffff0000u);
            float gx2 = __uint_as_float((g23 & 0xffffu) << 16);
            float gx3 = __uint_as_float(g23 & 0xffff0000u);
            short o4[4];
            o4[0] = f2bs(ot[qt][et][0] * inv * gx0);
            o4[1] = f2bs(ot[qt][et][1] * inv * gx1);
            o4[2] = f2bs(ot[qt][et][2] * inv * gx2);
            o4[3] = f2bs(ot[qt][et][3] * inv * gx3);
            *(uint2*)(TMP + row * DIM + e0) = *(uint2*)o4;
        }
    }
}

extern "C" void kernel_launch(void* const* d_in, const int* in_sizes, int n_in,
                              void* d_out, int out_size, void* d_ws, size_t ws_size,
                              hipStream_t stream) {
    const float* x     = (const float*)d_in[0];
    const float* lng_o = (const float*)d_in[1];
    const float* lnb_o = (const float*)d_in[2];
    const float* wq_o  = (const float*)d_in[3];
    const float* wkv_o = (const float*)d_in[4];
    const float* wo_o  = (const float*)d_in[5];
    const float* bo_o  = (const float*)d_in[6];
    const float* wg_o  = (const float*)d_in[7];
    const float* bg_o  = (const float*)d_in[8];
    const float* wb_o  = (const float*)d_in[9];
    const float* lng_i = (const float*)d_in[10];
    const float* lnb_i = (const float*)d_in[11];
    const float* wq_i  = (const float*)d_in[12];
    const float* wkv_i = (const float*)d_in[13];
    const float* wo_i  = (const float*)d_in[14];
    const float* bo_i  = (const float*)d_in[15];
    const float* wg_i  = (const float*)d_in[16];
    const float* bg_i  = (const float*)d_in[17];
    const float* wb_i  = (const float*)d_in[18];
    const float* lng_f = (const float*)d_in[19];
    const float* lnb_f = (const float*)d_in[20];
    const float* w1    = (const float*)d_in[21];
    const float* b1    = (const float*)d_in[22];
    const float* w2    = (const float*)d_in[23];
    const float* b2    = (const float*)d_in[24];

    const size_t T = (size_t)MROWS * DIM;
    char* base = (char*)d_ws;
    bf16*  XA    = (bf16*)base;  base += T * 2;            // bf16 LN output
    bf16*  XB    = (bf16*)base;  base += T * 2;            // bf16 copy of input x
    bf16*  X     = (bf16*)base;  base += T * 2;            // bf16 running residual
    bf16*  QKVb  = (bf16*)base;  base += 3 * T * 2;        // Q,K,V bf16 [3][4][MROWS][32]
    bf16*  Gb    = (bf16*)base;  base += T * 2;            // gate bf16 [MROWS][128]
    float* BIASb = (float*)base; base += (size_t)NH * MROWS * 4;
    bf16*  TMP   = (bf16*)base;  base += T * 2;            // o*gates bf16
    bf16*  WQKVG_O = (bf16*)base; base += 512 * 128 * 2;
    bf16*  WQKVG_I = (bf16*)base; base += 512 * 128 * 2;
    bf16*  WOT_O   = (bf16*)base; base += 128 * 128 * 2;
    bf16*  WOT_I   = (bf16*)base; base += 128 * 128 * 2;
    bf16*  W1PT    = (bf16*)base; base += 1024 * 128 * 2;
    bf16*  W2T     = (bf16*)base; base += 128 * 512 * 2;
    float* B1P     = (float*)base; base += 1024 * 4;
    bf16*  H2      = (bf16*)QKVb;  // overlay: QKVb+Gb free during FFN
    bf16*  Qhp = QKVb;
    bf16*  Khp = QKVb + T;
    bf16*  Vhp = QKVb + 2 * T;

    prep_kernel<<<1412 + MROWS / 4, 256, 0, stream>>>(
        wq_o, wkv_o, wg_o, wq_i, wkv_i, wg_i, wo_o, wo_i, w1, b1, w2,
        WQKVG_O, WQKVG_I, WOT_O, WOT_I, W1PT, W2T, B1P,
        x, lng_o, lnb_o, wb_o, XA, BIASb, XB);

    dim3 gQKVG(MROWS / 128, 4), gOUT(MROWS / 64, 1), gW1(MROWS / 128, 8);
    dim3 gFF2(MROWS / 64, 1);

    // ---- stage 1: row attention, XB -> X (OUT fuses LN2 + stage-2 bias proj) ----
    mfma_gemm<EPI_QKVG, 128, 128><<<gQKVG, 256, 0, stream>>>(
        XA, WQKVG_O, bg_o, nullptr, nullptr, QKVb, Gb,
        nullptr, nullptr, nullptr, nullptr, nullptr, 0);
    attn_mfma_kernel<<<NSEQ * NH, 256, 0, stream>>>(Qhp, Khp, Vhp, BIASb, Gb, TMP);
    mfma_gemm<EPI_OUT, 64, 128><<<gOUT, 256, 0, stream>>>(
        TMP, WOT_O, bo_o, XB, nullptr, X, nullptr,
        lng_i, lnb_i, wb_i, BIASb, XA, 0);

    // ---- stage 2: col attention, X -> X in place (OUT fuses final LN) ----
    mfma_gemm<EPI_QKVG, 128, 128><<<gQKVG, 256, 0, stream>>>(
        XA, WQKVG_I, bg_i, nullptr, nullptr, QKVb, Gb,
        nullptr, nullptr, nullptr, nullptr, nullptr, 0);
    attn_mfma_kernel<<<NSEQ * NH, 256, 0, stream>>>(Qhp, Khp, Vhp, BIASb, Gb, TMP);
    mfma_gemm<EPI_OUT, 64, 128><<<gOUT, 256, 0, stream>>>(
        TMP, WOT_I, bo_i, X, nullptr, X, nullptr,
        lng_f, lnb_f, nullptr, nullptr, XA, 1);

    // ---- FFN: H2 = geglu(XA@w1p+b1p); out = H2@w2 + b2 + X ----
    mfma_gemm<EPI_GEGLU, 128, 128><<<gW1, 256, 0, stream>>>(
        XA, W1PT, B1P, nullptr, nullptr, H2, nullptr,
        nullptr, nullptr, nullptr, nullptr, nullptr, 0);
    mfma_gemm<EPI_FF2, 64, 512><<<gFF2, 256, 0, stream>>>(
        H2, W2T, b2, X, (float*)d_out, nullptr, nullptr,
        nullptr, nullptr, nullptr, nullptr, nullptr, 0);
}